// Round 1
// baseline (455.332 us; speedup 1.0000x reference)
//
#include <hip/hip_runtime.h>
#include <math.h>

#define D_MODEL 2048
#define NE 8
#define TOKENS 16384
#define NBLK 512
#define SPR_T 256

// output layout (floats): probs[16384*8], idx[16384*2], topp[16384*2], aux[1]
#define OUT_IDX   131072
#define OUT_TOPP  163840
#define OUT_AUX   196608

// ws layout (bytes)
#define WS_SIM    0         // float[65536]   262144 B  (zeroed)
#define WS_SPR    262144    // double[1]      8 B       (zeroed)
#define WS_BP     262152    // double[512*8]  32768 B
#define WS_BC     294920    // double[512*8]  32768 B
#define WS_XN     327688    // float[256]     1024 B
#define WS_RN     328712    // float[256*8]   8192 B

// ---------------------------------------------------------------------------
// Main router kernel: logits (f64 acc) -> softmax -> top2 -> outputs +
// per-block partial P-sums and expert counts.
// 512 blocks x 256 threads; each wave handles 8 tokens. W staged in 64KB LDS.
// ---------------------------------------------------------------------------
__global__ __launch_bounds__(256) void router_main(
    const float* __restrict__ x, const float* __restrict__ W,
    float* __restrict__ out, double* __restrict__ blockP, double* __restrict__ blockC)
{
    __shared__ float Wl[NE * D_MODEL];  // 64 KB
    const int tid = threadIdx.x;
    const float4* W4 = (const float4*)W;
    float4* Wl4 = (float4*)Wl;
#pragma unroll
    for (int i = 0; i < 16; ++i) Wl4[tid + i * 256] = W4[tid + i * 256];
    __syncthreads();

    const int wave = tid >> 6, lane = tid & 63;
    const int t0 = blockIdx.x * 32 + wave * 8;

    double localP[NE], localC[NE];
#pragma unroll
    for (int e = 0; e < NE; ++e) { localP[e] = 0.0; localC[e] = 0.0; }

    for (int ti = 0; ti < 8; ++ti) {
        const int t = t0 + ti;
        const float4* xp = (const float4*)(x + (size_t)t * D_MODEL);
        double acc[NE];
#pragma unroll
        for (int e = 0; e < NE; ++e) acc[e] = 0.0;
#pragma unroll
        for (int it = 0; it < 8; ++it) {
            float4 xv = xp[it * 64 + lane];
#pragma unroll
            for (int e = 0; e < NE; ++e) {
                float4 wv = Wl4[e * 512 + it * 64 + lane];
                acc[e] += (double)xv.x * wv.x + (double)xv.y * wv.y +
                          (double)xv.z * wv.z + (double)xv.w * wv.w;
            }
        }
        // butterfly reduce each expert's partial across the 64 lanes
#pragma unroll
        for (int e = 0; e < NE; ++e) {
            double v = acc[e];
#pragma unroll
            for (int off = 32; off; off >>= 1) v += __shfl_xor(v, off, 64);
            acc[e] = v;
        }
        if (lane == 0) {
            // softmax in f32 (tolerance is loose); argmax on f64 logits
            double m = acc[0];
#pragma unroll
            for (int e = 1; e < NE; ++e) m = fmax(m, acc[e]);
            float p[NE]; float s = 0.f;
#pragma unroll
            for (int e = 0; e < NE; ++e) { p[e] = __expf((float)(acc[e] - m)); s += p[e]; }
            const float inv = 1.0f / s;
            // top-2, lowest index wins ties (jax.lax.top_k semantics)
            int i1 = 0; double v1 = acc[0];
#pragma unroll
            for (int e = 1; e < NE; ++e) if (acc[e] > v1) { v1 = acc[e]; i1 = e; }
            int i2 = -1; double v2 = -1e300;
#pragma unroll
            for (int e = 0; e < NE; ++e) if (e != i1 && acc[e] > v2) { v2 = acc[e]; i2 = e; }

            float pr[NE];
#pragma unroll
            for (int e = 0; e < NE; ++e) { pr[e] = p[e] * inv; localP[e] += (double)pr[e]; }
            localC[i1] += 1.0; localC[i2] += 1.0;

            float4* op = (float4*)(out + (size_t)t * NE);
            op[0] = make_float4(pr[0], pr[1], pr[2], pr[3]);
            op[1] = make_float4(pr[4], pr[5], pr[6], pr[7]);
            out[OUT_IDX + t * 2]     = (float)i1;
            out[OUT_IDX + t * 2 + 1] = (float)i2;
            const float ts = pr[i1] + pr[i2];
            out[OUT_TOPP + t * 2]     = pr[i1] / ts;
            out[OUT_TOPP + t * 2 + 1] = pr[i2] / ts;
        }
    }
    __syncthreads();             // done with Wl; reuse as reduction scratch
    double* redP = (double*)Wl;          // [4][8]
    double* redC = ((double*)Wl) + 32;   // [4][8]
    if (lane == 0) {
#pragma unroll
        for (int e = 0; e < NE; ++e) { redP[wave * 8 + e] = localP[e]; redC[wave * 8 + e] = localC[e]; }
    }
    __syncthreads();
    if (tid < NE) {
        double sp = 0, sc = 0;
#pragma unroll
        for (int w = 0; w < 4; ++w) { sp += redP[w * 8 + tid]; sc += redC[w * 8 + tid]; }
        blockP[blockIdx.x * NE + tid] = sp;
        blockC[blockIdx.x * NE + tid] = sc;
    }
}

// ---------------------------------------------------------------------------
// SPR: per-sampled-row x L2 norms + normalized router rows.
// 256 blocks x 256 threads (one block per sampled token).
// ---------------------------------------------------------------------------
__global__ void spr_norms(const float* __restrict__ x, const float* __restrict__ out,
                          const int* __restrict__ spr_idx,
                          float* __restrict__ xnorms, float* __restrict__ rnorm)
{
    const int i = blockIdx.x, tid = threadIdx.x;
    const int row = spr_idx[i];
    const float4* xp = (const float4*)(x + (size_t)row * D_MODEL);
    double s = 0.0;
#pragma unroll
    for (int k = 0; k < 2; ++k) {
        float4 v = xp[tid + k * 256];
        s += (double)v.x * v.x + (double)v.y * v.y + (double)v.z * v.z + (double)v.w * v.w;
    }
#pragma unroll
    for (int off = 32; off; off >>= 1) s += __shfl_xor(s, off, 64);
    __shared__ double red[4];
    const int wave = tid >> 6, lane = tid & 63;
    if (lane == 0) red[wave] = s;
    __syncthreads();
    if (tid == 0) {
        double tot = red[0] + red[1] + red[2] + red[3];
        xnorms[i] = (float)fmax(sqrt(tot), 1e-12);
        double rs = 0.0; float pv[NE];
#pragma unroll
        for (int e = 0; e < NE; ++e) { pv[e] = out[(size_t)row * NE + e]; rs += (double)pv[e] * pv[e]; }
        const double rn = fmax(sqrt(rs), 1e-12);
#pragma unroll
        for (int e = 0; e < NE; ++e) rnorm[i * NE + e] = (float)(pv[e] / rn);
    }
}

// ---------------------------------------------------------------------------
// SPR raw-dot GEMM, K-split for parallelism. grid (4,4,16), 256 thr.
// Each block: 64x64 pair tile over a 128-wide K slab (2 chunks of 64).
// 4x4 register blocking; partials atomically accumulated into ws sim[].
// ---------------------------------------------------------------------------
__global__ __launch_bounds__(256) void spr_gemm(
    const float* __restrict__ x, const int* __restrict__ spr_idx, float* __restrict__ sim)
{
    __shared__ float A[64][65];
    __shared__ float B[64][65];
    const int bi = blockIdx.x, bj = blockIdx.y, bk = blockIdx.z;
    const int tid = threadIdx.x;
    const int tx = tid & 15, ty = tid >> 4;
    float acc[4][4] = {};
    const int k0base = bk * 128;

    for (int kc = 0; kc < 2; ++kc) {
        const int k0 = k0base + kc * 64;
#pragma unroll
        for (int l = 0; l < 4; ++l) {
            const int lin = l * 256 + tid;
            const int r = lin >> 4, c4 = lin & 15;
            const int ga = spr_idx[bi * 64 + r];
            float4 v = *(const float4*)(x + (size_t)ga * D_MODEL + k0 + c4 * 4);
            A[r][c4 * 4] = v.x; A[r][c4 * 4 + 1] = v.y; A[r][c4 * 4 + 2] = v.z; A[r][c4 * 4 + 3] = v.w;
            const int gb = spr_idx[bj * 64 + r];
            float4 w = *(const float4*)(x + (size_t)gb * D_MODEL + k0 + c4 * 4);
            B[r][c4 * 4] = w.x; B[r][c4 * 4 + 1] = w.y; B[r][c4 * 4 + 2] = w.z; B[r][c4 * 4 + 3] = w.w;
        }
        __syncthreads();
#pragma unroll 4
        for (int k = 0; k < 64; ++k) {
            float a[4], b[4];
#pragma unroll
            for (int u = 0; u < 4; ++u) { a[u] = A[ty * 4 + u][k]; b[u] = B[tx * 4 + u][k]; }
#pragma unroll
            for (int u = 0; u < 4; ++u)
#pragma unroll
                for (int v = 0; v < 4; ++v) acc[u][v] += a[u] * b[v];
        }
        __syncthreads();
    }
#pragma unroll
    for (int u = 0; u < 4; ++u)
#pragma unroll
        for (int v = 0; v < 4; ++v) {
            const int i = bi * 64 + ty * 4 + u;
            const int j = bj * 64 + tx * 4 + v;
            atomicAdd(&sim[i * 256 + j], acc[u][v]);
        }
}

// ---------------------------------------------------------------------------
// SPR loss: input_sim via norms, routing_sim via rnorm dots, sum of sq diffs.
// grid 256 x 256 threads = 65536 pairs.
// ---------------------------------------------------------------------------
__global__ void spr_loss_k(const float* __restrict__ sim, const float* __restrict__ xnorms,
                           const float* __restrict__ rnorm, double* __restrict__ spr_sum)
{
    const int tid = threadIdx.x;
    const int p = blockIdx.x * 256 + tid;
    const int i = p >> 8, j = p & 255;
    const float isim = sim[p] / (xnorms[i] * xnorms[j]);
    float rs = 0.f;
#pragma unroll
    for (int e = 0; e < NE; ++e) rs += rnorm[i * NE + e] * rnorm[j * NE + e];
    const double d = (double)rs - (double)isim;
    double sq = d * d;
#pragma unroll
    for (int off = 32; off; off >>= 1) sq += __shfl_xor(sq, off, 64);
    __shared__ double red[4];
    const int wave = tid >> 6, lane = tid & 63;
    if (lane == 0) red[wave] = sq;
    __syncthreads();
    if (tid == 0) atomicAdd(spr_sum, red[0] + red[1] + red[2] + red[3]);
}

// ---------------------------------------------------------------------------
// Finalize aux loss.
// ---------------------------------------------------------------------------
__global__ void finalize(const double* __restrict__ blockP, const double* __restrict__ blockC,
                         const double* __restrict__ spr_sum, float* __restrict__ out)
{
    const int tid = threadIdx.x;  // 256 threads
    __shared__ double Ps[32][8], Cs[32][8];
    const int e = tid & 7, c = tid >> 3;  // 32 chunks of 16 blocks
    double sp = 0, sc = 0;
#pragma unroll
    for (int b = 0; b < 16; ++b) {
        sp += blockP[(c * 16 + b) * NE + e];
        sc += blockC[(c * 16 + b) * NE + e];
    }
    Ps[c][e] = sp; Cs[c][e] = sc;
    __syncthreads();
    if (tid == 0) {
        double lb = 0, dpsl = 0;
        for (int ee = 0; ee < NE; ++ee) {
            double P = 0, C = 0;
            for (int cc = 0; cc < 32; ++cc) { P += Ps[cc][ee]; C += Cs[cc][ee]; }
            const double Pi = P / (double)TOKENS;
            const double fi = C / (double)(TOKENS * 2);
            lb += fi * Pi;
            dpsl += 0.125 * (log(0.125) - log(Pi));
        }
        lb *= 8.0;
        const double spr = spr_sum[0] / 65536.0;
        out[OUT_AUX] = (float)(0.01 * (lb + dpsl + 0.1 * spr));
    }
}

extern "C" void kernel_launch(void* const* d_in, const int* in_sizes, int n_in,
                              void* d_out, int out_size, void* d_ws, size_t ws_size,
                              hipStream_t stream)
{
    const float* x = (const float*)d_in[0];
    const float* W = (const float*)d_in[1];
    const int* spr_idx = (const int*)d_in[2];
    float* out = (float*)d_out;
    char* ws = (char*)d_ws;

    float*  sim     = (float*)(ws + WS_SIM);
    double* spr_sum = (double*)(ws + WS_SPR);
    double* blockP  = (double*)(ws + WS_BP);
    double* blockC  = (double*)(ws + WS_BC);
    float*  xnorms  = (float*)(ws + WS_XN);
    float*  rnorm   = (float*)(ws + WS_RN);

    hipMemsetAsync(ws, 0, WS_BP, stream);  // zero sim + spr_sum

    router_main<<<NBLK, 256, 0, stream>>>(x, W, out, blockP, blockC);
    spr_norms<<<SPR_T, 256, 0, stream>>>(x, out, spr_idx, xnorms, rnorm);
    spr_gemm<<<dim3(4, 4, 16), 256, 0, stream>>>(x, spr_idx, sim);
    spr_loss_k<<<256, 256, 0, stream>>>(sim, xnorms, rnorm, spr_sum);
    finalize<<<1, 256, 0, stream>>>(blockP, blockC, spr_sum, out);
}

// Round 2
// 258.798 us; speedup vs baseline: 1.7594x; 1.7594x over previous
//
#include <hip/hip_runtime.h>
#include <math.h>

#define D_MODEL 2048
#define NE 8
#define TOKENS 16384

// output layout (floats): probs[16384*8], idx[16384*2], topp[16384*2], aux[1]
#define OUT_IDX   131072
#define OUT_TOPP  163840
#define OUT_AUX   196608

// ws layout (bytes)
#define WS_SPR    0        // double[1]      (zeroed)
#define WS_GP     8        // float[8]       (zeroed)
#define WS_GC     40       // float[8]       (zeroed)
#define WS_XN     72       // float[256]
#define WS_RN     1096     // float[256*8]
#define WS_SIMP   16384    // float[8][65536] = 2 MB, fully written by spr_gemm
#define KSPLIT    8

// ---------------------------------------------------------------------------
// Main router: logits (f64 acc) -> softmax -> top2.
// 256 blocks x 512 threads (8 waves); each wave owns 8 tokens.
// W staged in 64KB LDS. Token loop NOT unrolled (VGPR control).
// Epilogue is lane-parallel: lane = 8*expert + token within the wave.
// ---------------------------------------------------------------------------
__global__ __launch_bounds__(512) void router_main(
    const float* __restrict__ x, const float* __restrict__ W,
    float* __restrict__ out, float* __restrict__ gP, float* __restrict__ gC)
{
    __shared__ float4 Wl4[NE * D_MODEL / 4];   // 64 KB
    __shared__ float Pl[NE];
    __shared__ float Cl[NE];
    const int tid = threadIdx.x;
    {
        const float4* W4 = (const float4*)W;
#pragma unroll
        for (int i = 0; i < 8; ++i) Wl4[tid + i * 512] = W4[tid + i * 512];
    }
    if (tid < NE) { Pl[tid] = 0.f; Cl[tid] = 0.f; }
    __syncthreads();

    const int wave = tid >> 6, lane = tid & 63;
    const int t0 = (blockIdx.x * 8 + wave) * 8;    // first token of this wave
    const int e_mine = lane >> 3;                  // expert this lane owns in epilogue
    const int t_mine = lane & 7;                   // token this lane owns in epilogue
    double myL = 0.0;                              // stashed logit[e_mine] of token t_mine

#pragma unroll 1
    for (int t = 0; t < 8; ++t) {
        const float4* xp = (const float4*)(x + (size_t)(t0 + t) * D_MODEL);
        double acc[NE] = {0, 0, 0, 0, 0, 0, 0, 0};
#pragma unroll 4
        for (int it = 0; it < 8; ++it) {
            float4 xv = xp[it * 64 + lane];
            const double x0 = xv.x, x1 = xv.y, x2 = xv.z, x3 = xv.w;
#pragma unroll
            for (int e = 0; e < NE; ++e) {
                float4 wv = Wl4[e * 512 + it * 64 + lane];
                acc[e] += x0 * wv.x + x1 * wv.y + x2 * wv.z + x3 * wv.w;
            }
        }
        // full 64-lane butterfly per expert (result in all lanes)
#pragma unroll
        for (int e = 0; e < NE; ++e) {
            double v = acc[e];
#pragma unroll
            for (int off = 32; off; off >>= 1) v += __shfl_xor(v, off, 64);
            acc[e] = v;
        }
        // stash: lane (8e + t) keeps logit[e] of token t
        double sel = acc[0];
        sel = (e_mine == 1) ? acc[1] : sel;
        sel = (e_mine == 2) ? acc[2] : sel;
        sel = (e_mine == 3) ? acc[3] : sel;
        sel = (e_mine == 4) ? acc[4] : sel;
        sel = (e_mine == 5) ? acc[5] : sel;
        sel = (e_mine == 6) ? acc[6] : sel;
        sel = (e_mine == 7) ? acc[7] : sel;
        if (t_mine == t) myL = sel;
    }

    // ---- lane-parallel epilogue: octet = lanes {8e + t_mine, e=0..7} ----
    // argmax1 (f64, lowest index wins ties = jax.lax.top_k)
    double v1 = myL; int i1 = e_mine;
#pragma unroll
    for (int off = 8; off <= 32; off <<= 1) {
        double ov = __shfl_xor(v1, off, 64);
        int oi = __shfl_xor(i1, off, 64);
        if (ov > v1 || (ov == v1 && oi < i1)) { v1 = ov; i1 = oi; }
    }
    // argmax2 (mask out i1)
    double v2 = (e_mine == i1) ? -1e300 : myL;
    int i2 = (e_mine == i1) ? NE : e_mine;
#pragma unroll
    for (int off = 8; off <= 32; off <<= 1) {
        double ov = __shfl_xor(v2, off, 64);
        int oi = __shfl_xor(i2, off, 64);
        if (ov > v2 || (ov == v2 && oi < i2)) { v2 = ov; i2 = oi; }
    }
    // softmax (f32 is fine; threshold is 0.14)
    float p = __expf((float)(myL - v1));
    float s = p;
#pragma unroll
    for (int off = 8; off <= 32; off <<= 1) s += __shfl_xor(s, off, 64);
    const float pr = p / s;

    const int tg = t0 + t_mine;
    out[(size_t)tg * NE + e_mine] = pr;            // permuted-contiguous 256B/wave

    const float e2 = __expf((float)(v2 - v1));     // pr2/pr1
    if (e_mine == 0) {
        out[OUT_IDX + tg * 2] = (float)i1;
        out[OUT_TOPP + tg * 2] = 1.0f / (1.0f + e2);
    } else if (e_mine == 1) {
        out[OUT_IDX + tg * 2 + 1] = (float)i2;
        out[OUT_TOPP + tg * 2 + 1] = e2 / (1.0f + e2);
    }

    // P-sum / expert counts: LDS atomics (per-block), then 8 global atomics
    atomicAdd(&Pl[e_mine], pr);
    if (e_mine == i1) atomicAdd(&Cl[e_mine], 1.0f);
    if (e_mine == i2) atomicAdd(&Cl[e_mine], 1.0f);
    __syncthreads();
    if (tid < NE) {
        atomicAdd(&gP[tid], Pl[tid]);
        atomicAdd(&gC[tid], Cl[tid]);
    }
}

// ---------------------------------------------------------------------------
// SPR: per-sampled-row x L2 norms + normalized router rows.
// ---------------------------------------------------------------------------
__global__ void spr_norms(const float* __restrict__ x, const float* __restrict__ out,
                          const int* __restrict__ spr_idx,
                          float* __restrict__ xnorms, float* __restrict__ rnorm)
{
    const int i = blockIdx.x, tid = threadIdx.x;
    const int row = spr_idx[i];
    const float4* xp = (const float4*)(x + (size_t)row * D_MODEL);
    double s = 0.0;
#pragma unroll
    for (int k = 0; k < 2; ++k) {
        float4 v = xp[tid + k * 256];
        s += (double)v.x * v.x + (double)v.y * v.y + (double)v.z * v.z + (double)v.w * v.w;
    }
#pragma unroll
    for (int off = 32; off; off >>= 1) s += __shfl_xor(s, off, 64);
    __shared__ double red[4];
    const int wave = tid >> 6, lane = tid & 63;
    if (lane == 0) red[wave] = s;
    __syncthreads();
    if (tid == 0) {
        double tot = red[0] + red[1] + red[2] + red[3];
        xnorms[i] = (float)fmax(sqrt(tot), 1e-12);
        double rs = 0.0; float pv[NE];
#pragma unroll
        for (int e = 0; e < NE; ++e) { pv[e] = out[(size_t)row * NE + e]; rs += (double)pv[e] * pv[e]; }
        const double rn = fmax(sqrt(rs), 1e-12);
#pragma unroll
        for (int e = 0; e < NE; ++e) rnorm[i * NE + e] = (float)(pv[e] / rn);
    }
}

// ---------------------------------------------------------------------------
// SPR raw-dot GEMM, K-split 8, NO atomics: each bk writes its own partial.
// grid (4,4,8), 256 thr; block: 64x64 tile over a 256-wide K slab.
// ---------------------------------------------------------------------------
__global__ __launch_bounds__(256) void spr_gemm(
    const float* __restrict__ x, const int* __restrict__ spr_idx, float* __restrict__ simP)
{
    __shared__ float A[64][65];
    __shared__ float B[64][65];
    const int bi = blockIdx.x, bj = blockIdx.y, bk = blockIdx.z;
    const int tid = threadIdx.x;
    const int tx = tid & 15, ty = tid >> 4;
    float acc[4][4] = {};

    for (int kc = 0; kc < 4; ++kc) {
        const int k0 = bk * 256 + kc * 64;
#pragma unroll
        for (int l = 0; l < 4; ++l) {
            const int lin = l * 256 + tid;
            const int r = lin >> 4, c4 = lin & 15;
            const int ga = spr_idx[bi * 64 + r];
            float4 v = *(const float4*)(x + (size_t)ga * D_MODEL + k0 + c4 * 4);
            A[r][c4 * 4] = v.x; A[r][c4 * 4 + 1] = v.y; A[r][c4 * 4 + 2] = v.z; A[r][c4 * 4 + 3] = v.w;
            const int gb = spr_idx[bj * 64 + r];
            float4 w = *(const float4*)(x + (size_t)gb * D_MODEL + k0 + c4 * 4);
            B[r][c4 * 4] = w.x; B[r][c4 * 4 + 1] = w.y; B[r][c4 * 4 + 2] = w.z; B[r][c4 * 4 + 3] = w.w;
        }
        __syncthreads();
#pragma unroll 4
        for (int k = 0; k < 64; ++k) {
            float a[4], b[4];
#pragma unroll
            for (int u = 0; u < 4; ++u) { a[u] = A[ty * 4 + u][k]; b[u] = B[tx * 4 + u][k]; }
#pragma unroll
            for (int u = 0; u < 4; ++u)
#pragma unroll
                for (int v = 0; v < 4; ++v) acc[u][v] += a[u] * b[v];
        }
        __syncthreads();
    }
    float* dst = simP + (size_t)bk * 65536;
#pragma unroll
    for (int u = 0; u < 4; ++u)
#pragma unroll
        for (int v = 0; v < 4; ++v) {
            const int i = bi * 64 + ty * 4 + u;
            const int j = bj * 64 + tx * 4 + v;
            dst[i * 256 + j] = acc[u][v];
        }
}

// ---------------------------------------------------------------------------
// SPR loss: sum K-split partials, normalize, routing sims, sq-diff reduce.
// ---------------------------------------------------------------------------
__global__ void spr_loss_k(const float* __restrict__ simP, const float* __restrict__ xnorms,
                           const float* __restrict__ rnorm, double* __restrict__ spr_sum)
{
    const int tid = threadIdx.x;
    const int pidx = blockIdx.x * 256 + tid;
    const int i = pidx >> 8, j = pidx & 255;
    float raw = 0.f;
#pragma unroll
    for (int s8 = 0; s8 < KSPLIT; ++s8) raw += simP[(size_t)s8 * 65536 + pidx];
    const float isim = raw / (xnorms[i] * xnorms[j]);
    float rs = 0.f;
#pragma unroll
    for (int e = 0; e < NE; ++e) rs += rnorm[i * NE + e] * rnorm[j * NE + e];
    const double d = (double)rs - (double)isim;
    double sq = d * d;
#pragma unroll
    for (int off = 32; off; off >>= 1) sq += __shfl_xor(sq, off, 64);
    __shared__ double red[4];
    const int wave = tid >> 6, lane = tid & 63;
    if (lane == 0) red[wave] = sq;
    __syncthreads();
    if (tid == 0) atomicAdd(spr_sum, red[0] + red[1] + red[2] + red[3]);
}

// ---------------------------------------------------------------------------
// Finalize aux loss.
// ---------------------------------------------------------------------------
__global__ void finalize(const float* __restrict__ gP, const float* __restrict__ gC,
                         const double* __restrict__ spr_sum, float* __restrict__ out)
{
    if (threadIdx.x == 0) {
        double lb = 0, dpsl = 0;
        for (int e = 0; e < NE; ++e) {
            const double Pi = (double)gP[e] / (double)TOKENS;
            const double fi = (double)gC[e] / (double)(TOKENS * 2);
            lb += fi * Pi;
            dpsl += 0.125 * (log(0.125) - log(Pi));
        }
        lb *= 8.0;
        const double spr = spr_sum[0] / 65536.0;
        out[OUT_AUX] = (float)(0.01 * (lb + dpsl + 0.1 * spr));
    }
}

extern "C" void kernel_launch(void* const* d_in, const int* in_sizes, int n_in,
                              void* d_out, int out_size, void* d_ws, size_t ws_size,
                              hipStream_t stream)
{
    const float* x = (const float*)d_in[0];
    const float* W = (const float*)d_in[1];
    const int* spr_idx = (const int*)d_in[2];
    float* out = (float*)d_out;
    char* ws = (char*)d_ws;

    double* spr_sum = (double*)(ws + WS_SPR);
    float*  gP      = (float*)(ws + WS_GP);
    float*  gC      = (float*)(ws + WS_GC);
    float*  xnorms  = (float*)(ws + WS_XN);
    float*  rnorm   = (float*)(ws + WS_RN);
    float*  simP    = (float*)(ws + WS_SIMP);

    hipMemsetAsync(ws, 0, 72, stream);   // spr_sum + gP + gC

    router_main<<<256, 512, 0, stream>>>(x, W, out, gP, gC);
    spr_norms<<<256, 256, 0, stream>>>(x, out, spr_idx, xnorms, rnorm);
    spr_gemm<<<dim3(4, 4, 8), 256, 0, stream>>>(x, spr_idx, simP);
    spr_loss_k<<<256, 256, 0, stream>>>(simP, xnorms, rnorm, spr_sum);
    finalize<<<1, 64, 0, stream>>>(gP, gC, spr_sum, out);
}